// Round 1
// baseline (22610.191 us; speedup 1.0000x reference)
//
#include <hip/hip_runtime.h>
#include <math.h>

#define B_   32
#define L_   197
#define E_   384
#define DI_  768
#define DS_  16
#define DR_  24
#define NP_  196
#define ROWS (B_ * L_)        // 6304
#define OUT0 (ROWS * E_)      // 2420736
#define FEAT (B_ * E_ * NP_)  // 2408448

__device__ __forceinline__ float silu_f(float x) { return x / (1.f + __expf(-x)); }

// ---------------- im2col for patch embedding ----------------
__global__ __launch_bounds__(256) void im2col_kernel(const float* __restrict__ x,
                                                     float* __restrict__ xcol) {
    int idx = blockIdx.x * 256 + threadIdx.x;          // (b*196+pi)*768 + k
    if (idx >= B_ * NP_ * 768) return;
    int k = idx % 768;
    int bp = idx / 768;
    int pi = bp % NP_, b = bp / NP_;
    int gi = pi / 14, gj = pi % 14;
    int c = k >> 8, r = k & 255, p = r >> 4, q = r & 15;
    xcol[idx] = x[((size_t)(b * 3 + c) * 224 + gi * 16 + p) * 224 + gj * 16 + q];
}

// ---------------- assemble hidden: patches + cls + pos ----------------
__global__ __launch_bounds__(256) void assemble_kernel(const float* __restrict__ patchbuf,
                                                       const float* __restrict__ cls,
                                                       const float* __restrict__ pos,
                                                       float* __restrict__ hidden) {
    int idx = blockIdx.x * 256 + threadIdx.x;          // (b*197+tok)*384 + e
    if (idx >= ROWS * E_) return;
    int e = idx % E_;
    int bt = idx / E_;
    int tok = bt % L_, b = bt / L_;
    float v;
    if (tok == 98) v = cls[e];
    else {
        int pi = tok < 98 ? tok : tok - 1;
        v = patchbuf[(size_t)(b * NP_ + pi) * E_ + e];
    }
    hidden[idx] = v + pos[tok * E_ + e];
}

// ---------------- generic tiled GEMM: C = A(MxK,lda) * W(NxK)^T + bias ----------------
// act: 0 = none, 1 = softplus
__global__ __launch_bounds__(256) void gemm_kernel(const float* __restrict__ A, int lda,
                                                   const float* __restrict__ W,
                                                   const float* __restrict__ bias,
                                                   float* __restrict__ C, int ldc,
                                                   int M, int N, int K, int act) {
    __shared__ float As[16][68];
    __shared__ float Ws[16][68];
    const int tid = threadIdx.x;
    const int tx = tid & 15, ty = tid >> 4;
    const int bm = blockIdx.y * 64, bn = blockIdx.x * 64;
    float acc[4][4] = {};
    for (int k0 = 0; k0 < K; k0 += 16) {
#pragma unroll
        for (int i = 0; i < 4; ++i) {
            int e = i * 256 + tid;          // 0..1023
            int m = e >> 4, kk = e & 15;
            int gk = k0 + kk;
            int gm = bm + m;
            As[kk][m] = (gm < M && gk < K) ? A[(size_t)gm * lda + gk] : 0.f;
            int gn = bn + m;
            Ws[kk][m] = (gn < N && gk < K) ? W[(size_t)gn * K + gk] : 0.f;
        }
        __syncthreads();
#pragma unroll
        for (int kk = 0; kk < 16; ++kk) {
            float4 a4 = *(const float4*)&As[kk][ty * 4];
            float4 b4 = *(const float4*)&Ws[kk][tx * 4];
            float av[4] = {a4.x, a4.y, a4.z, a4.w};
            float bv[4] = {b4.x, b4.y, b4.z, b4.w};
#pragma unroll
            for (int i = 0; i < 4; ++i)
#pragma unroll
                for (int j = 0; j < 4; ++j) acc[i][j] += av[i] * bv[j];
        }
        __syncthreads();
    }
#pragma unroll
    for (int i = 0; i < 4; ++i) {
        int m = bm + ty * 4 + i;
        if (m >= M) continue;
#pragma unroll
        for (int j = 0; j < 4; ++j) {
            int n = bn + tx * 4 + j;
            if (n >= N) continue;
            float v = acc[i][j] + (bias ? bias[n] : 0.f);
            if (act == 1) v = (v > 20.f) ? v : log1pf(__expf(v));
            C[(size_t)m * ldc + n] = v;
        }
    }
}

// ---------------- fused residual += hidden ; out = LayerNorm(residual) ----------------
__global__ __launch_bounds__(256) void resid_ln_kernel(float* __restrict__ residual,
                                                       const float* __restrict__ hidden,
                                                       const float* __restrict__ w,
                                                       const float* __restrict__ b,
                                                       float* __restrict__ out,
                                                       int nrows) {
    int row = blockIdx.x * 4 + (threadIdx.x >> 6);
    int lane = threadIdx.x & 63;
    if (row >= nrows) return;
    const float* rp = residual + (size_t)row * E_;
    const float* hp = hidden + (size_t)row * E_;
    float v[6];
    float sum = 0.f;
#pragma unroll
    for (int i = 0; i < 6; ++i) {
        int c = lane + i * 64;
        float x = rp[c] + hp[c];
        v[i] = x;
        sum += x;
    }
#pragma unroll
    for (int o = 32; o; o >>= 1) sum += __shfl_xor(sum, o);
    float mean = sum * (1.f / E_);
    float vs = 0.f;
#pragma unroll
    for (int i = 0; i < 6; ++i) {
        float d = v[i] - mean;
        vs += d * d;
    }
#pragma unroll
    for (int o = 32; o; o >>= 1) vs += __shfl_xor(vs, o);
    float rstd = rsqrtf(vs * (1.f / E_) + 1e-5f);
#pragma unroll
    for (int i = 0; i < 6; ++i) {
        int c = lane + i * 64;
        residual[(size_t)row * E_ + c] = v[i];
        out[(size_t)row * E_ + c] = (v[i] - mean) * rstd * w[c] + b[c];
    }
}

// ---------------- causal conv1d + SiLU, direction-local output ----------------
__global__ __launch_bounds__(256) void conv_silu_kernel(const float* __restrict__ xz,
                                                        const float* __restrict__ cw,
                                                        const float* __restrict__ cb,
                                                        float* __restrict__ xc,
                                                        int rev) {
    int idx = blockIdx.x * 256 + threadIdx.x;          // (b*L+t)*768 + d
    if (idx >= B_ * L_ * DI_) return;
    int d = idx % DI_;
    int bt = idx / DI_;
    int t = bt % L_, b = bt / L_;
    float acc = cb[d];
#pragma unroll
    for (int k = 0; k < 4; ++k) {
        int tt = t - 3 + k;
        if (tt >= 0) {
            int pos = rev ? (L_ - 1 - tt) : tt;
            acc += cw[d * 4 + k] * xz[(size_t)(b * L_ + pos) * (2 * DI_) + d];
        }
    }
    xc[idx] = silu_f(acc);
}

// ---------------- SSM scan: 16 lanes per (b,d) channel, one lane per state ----------------
__global__ __launch_bounds__(256) void scan_kernel(const float* __restrict__ xc,
                                                   const float* __restrict__ xdbl,
                                                   const float* __restrict__ dt,
                                                   const float* __restrict__ xz,
                                                   const float* __restrict__ Alog,
                                                   const float* __restrict__ Dv,
                                                   float* __restrict__ ysum,
                                                   int rev, int accum) {
    int g = blockIdx.x * 16 + (threadIdx.x >> 4);      // b*768 + d
    int lane = threadIdx.x & 15;
    int b = g / DI_, d = g % DI_;
    float Aval = -__expf(Alog[d * DS_ + lane]);
    float Dval = Dv[d];
    float h = 0.f;
    for (int t = 0; t < L_; ++t) {
        int row = b * L_ + t;
        float dtv = dt[(size_t)row * DI_ + d];
        float u = xc[(size_t)row * DI_ + d];
        float Bt = xdbl[(size_t)row * 56 + 24 + lane];
        float Ct = xdbl[(size_t)row * 56 + 40 + lane];
        h = h * __expf(dtv * Aval) + (dtv * u) * Bt;
        float yp = h * Ct;
        yp += __shfl_xor(yp, 1);
        yp += __shfl_xor(yp, 2);
        yp += __shfl_xor(yp, 4);
        yp += __shfl_xor(yp, 8);
        if (lane == 0) {
            float y = yp + u * Dval;
            int pos = rev ? (L_ - 1 - t) : t;
            float zv = xz[(size_t)(b * L_ + pos) * (2 * DI_) + DI_ + d];
            float outv = 0.5f * y * silu_f(zv);
            float* p = &ysum[(size_t)(b * L_ + pos) * DI_ + d];
            *p = accum ? (*p + outv) : outv;
        }
    }
}

// ---------------- feature extraction ----------------
__global__ __launch_bounds__(256) void feat_kernel(const float* __restrict__ hidden,
                                                   float* __restrict__ out) {
    int idx = blockIdx.x * 256 + threadIdx.x;          // ((b*384+e)*196 + p)
    if (idx >= FEAT) return;
    int p = idx % NP_;
    int be = idx / NP_;
    int e = be % E_, b = be / E_;
    int tok = p < 98 ? p : p + 1;
    out[idx] = hidden[(size_t)(b * L_ + tok) * E_ + e];
}

static inline void launch_gemm(const float* A, int lda, const float* W, const float* bias,
                               float* C, int ldc, int M, int N, int K, int act,
                               hipStream_t stream) {
    dim3 grid((N + 63) / 64, (M + 63) / 64);
    hipLaunchKernelGGL(gemm_kernel, grid, dim3(256), 0, stream, A, lda, W, bias, C, ldc, M, N,
                       K, act);
}

extern "C" void kernel_launch(void* const* d_in, const int* in_sizes, int n_in, void* d_out,
                              int out_size, void* d_ws, size_t ws_size, hipStream_t stream) {
    const float* x        = (const float*)d_in[0];
    const float* patch_w  = (const float*)d_in[1];
    const float* patch_b  = (const float*)d_in[2];
    const float* cls_tok  = (const float*)d_in[3];
    const float* pos_emb  = (const float*)d_in[4];
    const float* norm_w   = (const float*)d_in[5];
    const float* norm_b   = (const float*)d_in[6];
    const float* in_proj  = (const float*)d_in[7];
    const float* conv_w   = (const float*)d_in[8];
    const float* conv_b   = (const float*)d_in[9];
    const float* xproj_w  = (const float*)d_in[10];
    const float* dtproj_w = (const float*)d_in[11];
    const float* dtproj_b = (const float*)d_in[12];
    const float* A_log    = (const float*)d_in[13];
    const float* D_param  = (const float*)d_in[14];
    const float* conv_wb  = (const float*)d_in[15];
    const float* conv_bb  = (const float*)d_in[16];
    const float* xproj_wb = (const float*)d_in[17];
    const float* dtproj_wb= (const float*)d_in[18];
    const float* dtproj_bb= (const float*)d_in[19];
    const float* A_logb   = (const float*)d_in[20];
    const float* D_paramb = (const float*)d_in[21];
    const float* out_proj = (const float*)d_in[22];
    const float* normf_w  = (const float*)d_in[23];
    const float* normf_b  = (const float*)d_in[24];
    float* out = (float*)d_out;

    float* ws       = (float*)d_ws;
    float* residual = ws;                        // 2,420,736
    float* hidden   = residual + OUT0;           // 2,420,736
    float* hn       = hidden + OUT0;             // 2,420,736
    float* xz       = hn + OUT0;                 // 9,682,944
    float* xc       = xz + (size_t)ROWS * 1536;  // 4,841,472
    float* xdbl     = xc + (size_t)ROWS * DI_;   //   353,024
    float* dtb      = xdbl + (size_t)ROWS * 56;  // 4,841,472
    float* ysum     = dtb + (size_t)ROWS * DI_;  // 4,841,472
    float* xcol     = xz;                        // overlay (pre-layer only)
    float* patchbuf = xc;                        // overlay (pre-layer only)

    // residual starts at zero (residual = hidden at layer 0)
    hipMemsetAsync(residual, 0, (size_t)OUT0 * sizeof(float), stream);

    // patch embedding
    hipLaunchKernelGGL(im2col_kernel, dim3((B_ * NP_ * 768 + 255) / 256), dim3(256), 0, stream,
                       x, xcol);
    launch_gemm(xcol, 768, patch_w, patch_b, patchbuf, E_, B_ * NP_, E_, 768, 0, stream);
    hipLaunchKernelGGL(assemble_kernel, dim3((ROWS * E_ + 255) / 256), dim3(256), 0, stream,
                       patchbuf, cls_tok, pos_emb, hidden);

    int fidx = 0;
    for (int i = 0; i < 24; ++i) {
        // residual += hidden ; hn = LN(residual)
        hipLaunchKernelGGL(resid_ln_kernel, dim3(ROWS / 4), dim3(256), 0, stream, residual,
                           hidden, norm_w + i * E_, norm_b + i * E_, hn, ROWS);
        // xz = hn @ in_proj^T
        launch_gemm(hn, E_, in_proj + (size_t)i * 1536 * E_, nullptr, xz, 1536, ROWS, 1536, E_,
                    0, stream);
        for (int dir = 0; dir < 2; ++dir) {
            const float* cw  = dir ? conv_wb : conv_w;
            const float* cb  = dir ? conv_bb : conv_b;
            const float* xw  = dir ? xproj_wb : xproj_w;
            const float* dtw = dir ? dtproj_wb : dtproj_w;
            const float* dtbi= dir ? dtproj_bb : dtproj_b;
            const float* Al  = dir ? A_logb : A_log;
            const float* Dv  = dir ? D_paramb : D_param;
            hipLaunchKernelGGL(conv_silu_kernel, dim3(B_ * L_ * DI_ / 256), dim3(256), 0,
                               stream, xz, cw + (size_t)i * DI_ * 4, cb + (size_t)i * DI_, xc,
                               dir);
            launch_gemm(xc, DI_, xw + (size_t)i * 56 * DI_, nullptr, xdbl, 56, ROWS, 56, DI_, 0,
                        stream);
            launch_gemm(xdbl, 56, dtw + (size_t)i * DI_ * DR_, dtbi + (size_t)i * DI_, dtb, DI_,
                        ROWS, DI_, DR_, 1, stream);
            hipLaunchKernelGGL(scan_kernel, dim3(B_ * DI_ / 16), dim3(256), 0, stream, xc, xdbl,
                               dtb, xz, Al + (size_t)i * DI_ * DS_, Dv + (size_t)i * DI_, ysum,
                               dir, dir);
        }
        // hidden = ysum @ out_proj^T
        launch_gemm(ysum, DI_, out_proj + (size_t)i * E_ * DI_, nullptr, hidden, E_, ROWS, E_,
                    DI_, 0, stream);
        if (i == 5 || i == 11 || i == 17 || i == 23) {
            hipLaunchKernelGGL(feat_kernel, dim3(FEAT / 256), dim3(256), 0, stream, hidden,
                               out + OUT0 + (size_t)fidx * FEAT);
            ++fidx;
        }
    }
    // final: residual += hidden ; out = LN(residual)
    hipLaunchKernelGGL(resid_ln_kernel, dim3(ROWS / 4), dim3(256), 0, stream, residual, hidden,
                       normf_w, normf_b, out, ROWS);
}

// Round 2
// 19311.375 us; speedup vs baseline: 1.1708x; 1.1708x over previous
//
#include <hip/hip_runtime.h>
#include <math.h>

#define B_   32
#define L_   197
#define E_   384
#define DI_  768
#define DS_  16
#define DR_  24
#define NP_  196
#define ROWS (B_ * L_)        // 6304
#define OUT0 (ROWS * E_)      // 2420736
#define FEAT (B_ * E_ * NP_)  // 2408448

typedef __attribute__((ext_vector_type(8))) short bf16x8;
typedef __attribute__((ext_vector_type(4))) float f32x4;

__device__ __forceinline__ float silu_f(float x) { return x / (1.f + __expf(-x)); }

__device__ __forceinline__ unsigned short f2bf(float x) {
    unsigned int u = __float_as_uint(x);
    u += 0x7fffu + ((u >> 16) & 1u);
    return (unsigned short)(u >> 16);
}

// ---------------- im2col for patch embedding ----------------
__global__ __launch_bounds__(256) void im2col_kernel(const float* __restrict__ x,
                                                     float* __restrict__ xcol) {
    int idx = blockIdx.x * 256 + threadIdx.x;          // (b*196+pi)*768 + k
    if (idx >= B_ * NP_ * 768) return;
    int k = idx % 768;
    int bp = idx / 768;
    int pi = bp % NP_, b = bp / NP_;
    int gi = pi / 14, gj = pi % 14;
    int c = k >> 8, r = k & 255, p = r >> 4, q = r & 15;
    xcol[idx] = x[((size_t)(b * 3 + c) * 224 + gi * 16 + p) * 224 + gj * 16 + q];
}

// ---------------- assemble hidden: patches + cls + pos ----------------
__global__ __launch_bounds__(256) void assemble_kernel(const float* __restrict__ patchbuf,
                                                       const float* __restrict__ cls,
                                                       const float* __restrict__ pos,
                                                       float* __restrict__ hidden) {
    int idx = blockIdx.x * 256 + threadIdx.x;          // (b*197+tok)*384 + e
    if (idx >= ROWS * E_) return;
    int e = idx % E_;
    int bt = idx / E_;
    int tok = bt % L_, b = bt / L_;
    float v;
    if (tok == 98) v = cls[e];
    else {
        int pi = tok < 98 ? tok : tok - 1;
        v = patchbuf[(size_t)(b * NP_ + pi) * E_ + e];
    }
    hidden[idx] = v + pos[tok * E_ + e];
}

// ---------------- bf16 MFMA GEMM: C = A(MxK fp32,lda) * W(NxK fp32)^T + bias ----------------
// act: 0 = none, 1 = softplus. On-the-fly fp32->bf16 conversion during LDS staging.
// Tile 128x128xBK32, 4 waves (2x2), each wave 4x4 fragments of 16x16x32.
__global__ __launch_bounds__(256) void gemm_mfma_kernel(const float* __restrict__ A, int lda,
                                                        const float* __restrict__ W,
                                                        const float* __restrict__ bias,
                                                        float* __restrict__ C, int ldc,
                                                        int M, int N, int K, int act) {
    __shared__ unsigned short As[128][32];
    __shared__ unsigned short Ws[128][32];
    const int tid = threadIdx.x;
    const int wave = tid >> 6;
    const int lane = tid & 63;
    const int wr = wave >> 1, wc = wave & 1;
    const int bm = blockIdx.y * 128, bn = blockIdx.x * 128;
    const int fr = lane & 15;   // fragment row (A) / col (B,D)
    const int fq = lane >> 4;   // k-group; D row-quad
    const int r = tid >> 3;     // staging row base 0..31
    const int c4 = tid & 7;     // staging col-quad 0..7
    f32x4 acc[4][4] = {};

    for (int k0 = 0; k0 < K; k0 += 32) {
        __syncthreads();
        const int kbase = k0 + c4 * 4;
        const bool kfull = (kbase + 4 <= K);
#pragma unroll
        for (int it = 0; it < 4; ++it) {
            int row = it * 32 + r;
            // A tile
            int gm = bm + row;
            float4 va = {0.f, 0.f, 0.f, 0.f};
            if (gm < M) {
                if (kfull) va = *(const float4*)&A[(size_t)gm * lda + kbase];
                else {
                    const float* ap = &A[(size_t)gm * lda];
                    if (kbase + 0 < K) va.x = ap[kbase + 0];
                    if (kbase + 1 < K) va.y = ap[kbase + 1];
                    if (kbase + 2 < K) va.z = ap[kbase + 2];
                    if (kbase + 3 < K) va.w = ap[kbase + 3];
                }
            }
            ushort4 ua = {f2bf(va.x), f2bf(va.y), f2bf(va.z), f2bf(va.w)};
            *(ushort4*)&As[row][c4 * 4] = ua;
            // W tile
            int gn = bn + row;
            float4 vw = {0.f, 0.f, 0.f, 0.f};
            if (gn < N) {
                if (kfull) vw = *(const float4*)&W[(size_t)gn * K + kbase];
                else {
                    const float* wp = &W[(size_t)gn * K];
                    if (kbase + 0 < K) vw.x = wp[kbase + 0];
                    if (kbase + 1 < K) vw.y = wp[kbase + 1];
                    if (kbase + 2 < K) vw.z = wp[kbase + 2];
                    if (kbase + 3 < K) vw.w = wp[kbase + 3];
                }
            }
            ushort4 uw = {f2bf(vw.x), f2bf(vw.y), f2bf(vw.z), f2bf(vw.w)};
            *(ushort4*)&Ws[row][c4 * 4] = uw;
        }
        __syncthreads();
        bf16x8 af[4], bfr[4];
#pragma unroll
        for (int i = 0; i < 4; ++i) {
            af[i]  = *(const bf16x8*)&As[wr * 64 + i * 16 + fr][fq * 8];
            bfr[i] = *(const bf16x8*)&Ws[wc * 64 + i * 16 + fr][fq * 8];
        }
#pragma unroll
        for (int i = 0; i < 4; ++i)
#pragma unroll
            for (int j = 0; j < 4; ++j)
                acc[i][j] =
                    __builtin_amdgcn_mfma_f32_16x16x32_bf16(af[i], bfr[j], acc[i][j], 0, 0, 0);
    }

#pragma unroll
    for (int j = 0; j < 4; ++j) {
        int n = bn + wc * 64 + j * 16 + fr;
        if (n >= N) continue;
        float bv = bias ? bias[n] : 0.f;
#pragma unroll
        for (int i = 0; i < 4; ++i) {
#pragma unroll
            for (int rr = 0; rr < 4; ++rr) {
                int m = bm + wr * 64 + i * 16 + fq * 4 + rr;
                if (m < M) {
                    float v = acc[i][j][rr] + bv;
                    if (act == 1) v = (v > 20.f) ? v : log1pf(__expf(v));
                    C[(size_t)m * ldc + n] = v;
                }
            }
        }
    }
}

// ---------------- fused residual += hidden ; out = LayerNorm(residual) ----------------
__global__ __launch_bounds__(256) void resid_ln_kernel(float* __restrict__ residual,
                                                       const float* __restrict__ hidden,
                                                       const float* __restrict__ w,
                                                       const float* __restrict__ b,
                                                       float* __restrict__ out,
                                                       int nrows) {
    int row = blockIdx.x * 4 + (threadIdx.x >> 6);
    int lane = threadIdx.x & 63;
    if (row >= nrows) return;
    const float* rp = residual + (size_t)row * E_;
    const float* hp = hidden + (size_t)row * E_;
    float v[6];
    float sum = 0.f;
#pragma unroll
    for (int i = 0; i < 6; ++i) {
        int c = lane + i * 64;
        float x = rp[c] + hp[c];
        v[i] = x;
        sum += x;
    }
#pragma unroll
    for (int o = 32; o; o >>= 1) sum += __shfl_xor(sum, o);
    float mean = sum * (1.f / E_);
    float vs = 0.f;
#pragma unroll
    for (int i = 0; i < 6; ++i) {
        float d = v[i] - mean;
        vs += d * d;
    }
#pragma unroll
    for (int o = 32; o; o >>= 1) vs += __shfl_xor(vs, o);
    float rstd = rsqrtf(vs * (1.f / E_) + 1e-5f);
#pragma unroll
    for (int i = 0; i < 6; ++i) {
        int c = lane + i * 64;
        residual[(size_t)row * E_ + c] = v[i];
        out[(size_t)row * E_ + c] = (v[i] - mean) * rstd * w[c] + b[c];
    }
}

// ---------------- causal conv1d + SiLU, direction-local output ----------------
__global__ __launch_bounds__(256) void conv_silu_kernel(const float* __restrict__ xz,
                                                        const float* __restrict__ cw,
                                                        const float* __restrict__ cb,
                                                        float* __restrict__ xc,
                                                        int rev) {
    int idx = blockIdx.x * 256 + threadIdx.x;          // (b*L+t)*768 + d
    if (idx >= B_ * L_ * DI_) return;
    int d = idx % DI_;
    int bt = idx / DI_;
    int t = bt % L_, b = bt / L_;
    float acc = cb[d];
#pragma unroll
    for (int k = 0; k < 4; ++k) {
        int tt = t - 3 + k;
        if (tt >= 0) {
            int pos = rev ? (L_ - 1 - tt) : tt;
            acc += cw[d * 4 + k] * xz[(size_t)(b * L_ + pos) * (2 * DI_) + d];
        }
    }
    xc[idx] = silu_f(acc);
}

// ---------------- SSM scan: 16 lanes per (b,d) channel, one lane per state ----------------
__global__ __launch_bounds__(256) void scan_kernel(const float* __restrict__ xc,
                                                   const float* __restrict__ xdbl,
                                                   const float* __restrict__ dt,
                                                   const float* __restrict__ xz,
                                                   const float* __restrict__ Alog,
                                                   const float* __restrict__ Dv,
                                                   float* __restrict__ ysum,
                                                   int rev, int accum) {
    int g = blockIdx.x * 16 + (threadIdx.x >> 4);      // b*768 + d
    int lane = threadIdx.x & 15;
    int b = g / DI_, d = g % DI_;
    float Aval = -__expf(Alog[d * DS_ + lane]);
    float Dval = Dv[d];
    float h = 0.f;
    for (int t = 0; t < L_; ++t) {
        int row = b * L_ + t;
        float dtv = dt[(size_t)row * DI_ + d];
        float u = xc[(size_t)row * DI_ + d];
        float Bt = xdbl[(size_t)row * 56 + 24 + lane];
        float Ct = xdbl[(size_t)row * 56 + 40 + lane];
        h = h * __expf(dtv * Aval) + (dtv * u) * Bt;
        float yp = h * Ct;
        yp += __shfl_xor(yp, 1);
        yp += __shfl_xor(yp, 2);
        yp += __shfl_xor(yp, 4);
        yp += __shfl_xor(yp, 8);
        if (lane == 0) {
            float y = yp + u * Dval;
            int pos = rev ? (L_ - 1 - t) : t;
            float zv = xz[(size_t)(b * L_ + pos) * (2 * DI_) + DI_ + d];
            float outv = 0.5f * y * silu_f(zv);
            float* p = &ysum[(size_t)(b * L_ + pos) * DI_ + d];
            *p = accum ? (*p + outv) : outv;
        }
    }
}

// ---------------- feature extraction ----------------
__global__ __launch_bounds__(256) void feat_kernel(const float* __restrict__ hidden,
                                                   float* __restrict__ out) {
    int idx = blockIdx.x * 256 + threadIdx.x;          // ((b*384+e)*196 + p)
    if (idx >= FEAT) return;
    int p = idx % NP_;
    int be = idx / NP_;
    int e = be % E_, b = be / E_;
    int tok = p < 98 ? p : p + 1;
    out[idx] = hidden[(size_t)(b * L_ + tok) * E_ + e];
}

static inline void launch_gemm(const float* A, int lda, const float* W, const float* bias,
                               float* C, int ldc, int M, int N, int K, int act,
                               hipStream_t stream) {
    dim3 grid((N + 127) / 128, (M + 127) / 128);
    hipLaunchKernelGGL(gemm_mfma_kernel, grid, dim3(256), 0, stream, A, lda, W, bias, C, ldc, M,
                       N, K, act);
}

extern "C" void kernel_launch(void* const* d_in, const int* in_sizes, int n_in, void* d_out,
                              int out_size, void* d_ws, size_t ws_size, hipStream_t stream) {
    const float* x        = (const float*)d_in[0];
    const float* patch_w  = (const float*)d_in[1];
    const float* patch_b  = (const float*)d_in[2];
    const float* cls_tok  = (const float*)d_in[3];
    const float* pos_emb  = (const float*)d_in[4];
    const float* norm_w   = (const float*)d_in[5];
    const float* norm_b   = (const float*)d_in[6];
    const float* in_proj  = (const float*)d_in[7];
    const float* conv_w   = (const float*)d_in[8];
    const float* conv_b   = (const float*)d_in[9];
    const float* xproj_w  = (const float*)d_in[10];
    const float* dtproj_w = (const float*)d_in[11];
    const float* dtproj_b = (const float*)d_in[12];
    const float* A_log    = (const float*)d_in[13];
    const float* D_param  = (const float*)d_in[14];
    const float* conv_wb  = (const float*)d_in[15];
    const float* conv_bb  = (const float*)d_in[16];
    const float* xproj_wb = (const float*)d_in[17];
    const float* dtproj_wb= (const float*)d_in[18];
    const float* dtproj_bb= (const float*)d_in[19];
    const float* A_logb   = (const float*)d_in[20];
    const float* D_paramb = (const float*)d_in[21];
    const float* out_proj = (const float*)d_in[22];
    const float* normf_w  = (const float*)d_in[23];
    const float* normf_b  = (const float*)d_in[24];
    float* out = (float*)d_out;

    float* ws       = (float*)d_ws;
    float* residual = ws;                        // 2,420,736
    float* hidden   = residual + OUT0;           // 2,420,736
    float* hn       = hidden + OUT0;             // 2,420,736
    float* xz       = hn + OUT0;                 // 9,682,944
    float* xc       = xz + (size_t)ROWS * 1536;  // 4,841,472
    float* xdbl     = xc + (size_t)ROWS * DI_;   //   353,024
    float* dtb      = xdbl + (size_t)ROWS * 56;  // 4,841,472
    float* ysum     = dtb + (size_t)ROWS * DI_;  // 4,841,472
    float* xcol     = xz;                        // overlay (pre-layer only)
    float* patchbuf = xc;                        // overlay (pre-layer only)

    hipMemsetAsync(residual, 0, (size_t)OUT0 * sizeof(float), stream);

    // patch embedding
    hipLaunchKernelGGL(im2col_kernel, dim3((B_ * NP_ * 768 + 255) / 256), dim3(256), 0, stream,
                       x, xcol);
    launch_gemm(xcol, 768, patch_w, patch_b, patchbuf, E_, B_ * NP_, E_, 768, 0, stream);
    hipLaunchKernelGGL(assemble_kernel, dim3((ROWS * E_ + 255) / 256), dim3(256), 0, stream,
                       patchbuf, cls_tok, pos_emb, hidden);

    int fidx = 0;
    for (int i = 0; i < 24; ++i) {
        hipLaunchKernelGGL(resid_ln_kernel, dim3(ROWS / 4), dim3(256), 0, stream, residual,
                           hidden, norm_w + i * E_, norm_b + i * E_, hn, ROWS);
        launch_gemm(hn, E_, in_proj + (size_t)i * 1536 * E_, nullptr, xz, 1536, ROWS, 1536, E_,
                    0, stream);
        for (int dir = 0; dir < 2; ++dir) {
            const float* cw  = dir ? conv_wb : conv_w;
            const float* cb  = dir ? conv_bb : conv_b;
            const float* xw  = dir ? xproj_wb : xproj_w;
            const float* dtw = dir ? dtproj_wb : dtproj_w;
            const float* dtbi= dir ? dtproj_bb : dtproj_b;
            const float* Al  = dir ? A_logb : A_log;
            const float* Dv  = dir ? D_paramb : D_param;
            hipLaunchKernelGGL(conv_silu_kernel, dim3(B_ * L_ * DI_ / 256), dim3(256), 0,
                               stream, xz, cw + (size_t)i * DI_ * 4, cb + (size_t)i * DI_, xc,
                               dir);
            launch_gemm(xc, DI_, xw + (size_t)i * 56 * DI_, nullptr, xdbl, 56, ROWS, 56, DI_, 0,
                        stream);
            launch_gemm(xdbl, 56, dtw + (size_t)i * DI_ * DR_, dtbi + (size_t)i * DI_, dtb, DI_,
                        ROWS, DI_, DR_, 1, stream);
            hipLaunchKernelGGL(scan_kernel, dim3(B_ * DI_ / 16), dim3(256), 0, stream, xc, xdbl,
                               dtb, xz, Al + (size_t)i * DI_ * DS_, Dv + (size_t)i * DI_, ysum,
                               dir, dir);
        }
        launch_gemm(ysum, DI_, out_proj + (size_t)i * E_ * DI_, nullptr, hidden, E_, ROWS, E_,
                    DI_, 0, stream);
        if (i == 5 || i == 11 || i == 17 || i == 23) {
            hipLaunchKernelGGL(feat_kernel, dim3(FEAT / 256), dim3(256), 0, stream, hidden,
                               out + OUT0 + (size_t)fidx * FEAT);
            ++fidx;
        }
    }
    hipLaunchKernelGGL(resid_ln_kernel, dim3(ROWS / 4), dim3(256), 0, stream, residual, hidden,
                       normf_w, normf_b, out, ROWS);
}